// Round 1
// 260.626 us; speedup vs baseline: 1.0258x; 1.0258x over previous
//
#include <hip/hip_runtime.h>

#define CH 64
#define HW 3136
#define MTOT 401408   // 128*3136

typedef __attribute__((ext_vector_type(8))) short short8;   // 8 bf16 (4 VGPRs)
typedef __attribute__((ext_vector_type(4))) float f32x4;
typedef __attribute__((ext_vector_type(4))) unsigned int u32x4;

// ---------------- K1: covariance via split-bf16 MFMA ----------------
// Sigma = x@x^T (x: [64][m] fp32) via hi/lo bf16 split:
//   Sigma ~= Xh@Xh^T + Xh@Xl^T + Xl@Xh^T   (lo@lo ~ 2^-19 rel, dropped)
// 784 blocks * 4 waves; each wave owns 4 K-steps of 32 px (12544 steps total).
// Only lower-triangle 16x16 blocks accumulated (Sigma symmetric).
// mfma_f32_16x16x32_bf16 layouts:
//   A frag: row = lane&15, k = (lane>>4)*8 + j  (8 consecutive px -> 2 float4 loads)
//   B frag == same registers (B^T = x), col = lane&15
//   C/D:    col = lane&15, row = (lane>>4)*4 + reg   [HW-verified m89/m91]
__device__ __forceinline__ void split8(const float4 a, const float4 b,
                                       short8& hi, short8& lo, float& ssum){
  const float f[8] = {a.x,a.y,a.z,a.w, b.x,b.y,b.z,b.w};
  u32x4 hp, lp;
#pragma unroll
  for (int j=0;j<4;++j){
    const unsigned int b0 = __float_as_uint(f[2*j]);
    const unsigned int b1 = __float_as_uint(f[2*j+1]);
    hp[j] = (b0 >> 16) | (b1 & 0xFFFF0000u);
    const float h0 = __uint_as_float(b0 & 0xFFFF0000u);
    const float h1 = __uint_as_float(b1 & 0xFFFF0000u);
    const unsigned int l0 = __float_as_uint(f[2*j]   - h0);
    const unsigned int l1 = __float_as_uint(f[2*j+1] - h1);
    lp[j] = (l0 >> 16) | (l1 & 0xFFFF0000u);
  }
  hi = __builtin_bit_cast(short8, hp);
  lo = __builtin_bit_cast(short8, lp);
  ssum += ((f[0]+f[1])+(f[2]+f[3])) + ((f[4]+f[5])+(f[6]+f[7]));
}

__global__ __launch_bounds__(256) void k1_cov(const float* __restrict__ X,
                                              float* __restrict__ SR){
  // lower-triangle block list (rg >= cg)
  constexpr int RG[10] = {0,1,1,2,2,2,3,3,3,3};
  constexpr int CG[10] = {0,0,1,0,1,2,0,1,2,3};
  __shared__ float red[4096];
  __shared__ float chs[64];

  const int t   = threadIdx.x;
  const int wid = __builtin_amdgcn_readfirstlane(t >> 6);
  const int l   = t & 63;
  const int wg  = blockIdx.x * 4 + wid;          // 0..3135
  const int lrow = l & 15;
  const int lk   = (l >> 4) * 8;

  f32x4 acc[10];
#pragma unroll
  for (int bi=0; bi<10; ++bi) acc[bi] = (f32x4){0.f,0.f,0.f,0.f};
  float sums[4] = {0.f,0.f,0.f,0.f};

  for (int i=0; i<4; ++i){
    const int s = wg*4 + i;                      // 0..12543
    const int b = s / 98;                        // image (98 steps of 32px per image)
    const int p = (s - b*98) * 32;               // px offset within image
    const float* base = X + (size_t)b*(CH*HW) + p + lrow*HW + lk;
    short8 fh[4], fl[4];
#pragma unroll
    for (int g=0; g<4; ++g){
      const float* pg = base + (size_t)g*16*HW;
      const float4 v0 = *(const float4*)pg;
      const float4 v1 = *(const float4*)(pg + 4);
      split8(v0, v1, fh[g], fl[g], sums[g]);
    }
#pragma unroll
    for (int bi=0; bi<10; ++bi){
      acc[bi] = __builtin_amdgcn_mfma_f32_16x16x32_bf16(fh[RG[bi]], fh[CG[bi]], acc[bi], 0,0,0);
      acc[bi] = __builtin_amdgcn_mfma_f32_16x16x32_bf16(fh[RG[bi]], fl[CG[bi]], acc[bi], 0,0,0);
      acc[bi] = __builtin_amdgcn_mfma_f32_16x16x32_bf16(fl[RG[bi]], fh[CG[bi]], acc[bi], 0,0,0);
    }
  }

  // wave-level channel-sum reduce across the 4 k-subgroups (lanes ^16, ^32)
#pragma unroll
  for (int g=0; g<4; ++g){
    sums[g] += __shfl_xor(sums[g], 16);
    sums[g] += __shfl_xor(sums[g], 32);
  }

  // deterministic cross-wave reduction in LDS
  for (int w=0; w<4; ++w){
    if (wid == w){
#pragma unroll
      for (int bi=0; bi<10; ++bi){
        const int row0 = RG[bi]*16 + 4*(l>>4);
        const int col  = CG[bi]*16 + (l&15);
#pragma unroll
        for (int r=0; r<4; ++r){
          float* d = &red[(row0+r)*64 + col];
          if (w==0) *d = acc[bi][r]; else *d += acc[bi][r];
        }
      }
      if (l < 16){
#pragma unroll
        for (int g=0; g<4; ++g){
          if (w==0) chs[g*16+l] = sums[g]; else chs[g*16+l] += sums[g];
        }
      }
    }
    __syncthreads();
  }

  // global accumulation (SR pre-zeroed); only lower-triangle blocks written
#pragma unroll
  for (int bi=0; bi<10; ++bi){
    const int r = RG[bi]*16 + (t>>4);
    const int c = CG[bi]*16 + (t&15);
    unsafeAtomicAdd(&SR[r*64+c], red[r*64+c]);
  }
  if (t < 64) unsafeAtomicAdd(&SR[4096+t], chs[t]);
}

// ---------------- K2: whitening matrix ----------------
// out = alpha*(a^T b) + beta_*aff ; a symmetric in all our uses.
__device__ __forceinline__ void mm_AtB(const float* a, const float* b, float* out,
                                       float alpha, const float* aff, float beta_){
  const int t = threadIdx.x;
  const int c2 = 2*(t & 31);
  const int r0 = 8*(t >> 5);
  float acc[8][2];
#pragma unroll
  for (int i=0;i<8;++i){ acc[i][0]=0.f; acc[i][1]=0.f; }
  for (int k=0;k<64;++k){
    const float2 bv = *(const float2*)&b[k*64 + c2];
    const float4 a0 = *(const float4*)&a[k*64 + r0];
    const float4 a1 = *(const float4*)&a[k*64 + r0 + 4];
    const float av[8] = {a0.x,a0.y,a0.z,a0.w, a1.x,a1.y,a1.z,a1.w};
#pragma unroll
    for (int i=0;i<8;++i){ acc[i][0] += av[i]*bv.x; acc[i][1] += av[i]*bv.y; }
  }
  float res[8][2];
#pragma unroll
  for (int i=0;i<8;++i){
    float f0 = alpha*acc[i][0], f1 = alpha*acc[i][1];
    if (aff){ f0 += beta_*aff[(r0+i)*64 + c2]; f1 += beta_*aff[(r0+i)*64 + c2 + 1]; }
    res[i][0]=f0; res[i][1]=f1;
  }
  __syncthreads();
#pragma unroll
  for (int i=0;i<8;++i){
    float2 o2; o2.x = res[i][0]; o2.y = res[i][1];
    *(float2*)&out[(r0+i)*64 + c2] = o2;
  }
  __syncthreads();
}

__global__ __launch_bounds__(256) void k2_wm(const float* __restrict__ SR,
                                             const float* __restrict__ beta,
                                             float* __restrict__ WM,
                                             float* __restrict__ OFS){
  __shared__ __align__(16) float bufE[4096];
  __shared__ __align__(16) float bufA[4096];
  __shared__ __align__(16) float bufB[4096];
  __shared__ float meanv[64];
  __shared__ float scal[2];
  const int t = threadIdx.x;
  const float inv_m = 1.f/(float)MTOT;
  if (t < 64) meanv[t] = SR[4096 + t]*inv_m;
  __syncthreads();
  // E = Sigma - I  (Sigma includes eps on diag and 0.9 off-diag fix)
  // SR holds only the lower-triangle 16x16 blocks: symmetrize on load.
  for (int idx=t; idx<4096; idx+=256){
    const int r = idx >> 6, c = idx & 63;
    const int src = ((r >> 4) >= (c >> 4)) ? idx : (c*64 + r);
    const float cov = SR[src]*inv_m - meanv[r]*meanv[c];
    bufE[idx] = (r==c) ? (cov + 1e-5f - 1.f) : 0.9f*cov;
  }
  __syncthreads();
  float n2 = 0.f, tr = 0.f;
  for (int idx=t; idx<4096; idx+=256){
    const float e = bufE[idx];
    n2 += e*e;
    if ((idx >> 6) == (idx & 63)) tr += e;
  }
  bufA[t] = n2; bufB[t] = tr;
  __syncthreads();
  if (t < 64){
    bufA[t] = bufA[t]+bufA[t+64]+bufA[t+128]+bufA[t+192];
    bufB[t] = bufB[t]+bufB[t+64]+bufB[t+128]+bufB[t+192];
  }
  __syncthreads();
  if (t == 0){
    float s1=0.f, s2=0.f;
    for (int i=0;i<64;++i){ s1 += bufA[i]; s2 += bufB[i]; }
    scal[0] = s1; scal[1] = s2;
  }
  __syncthreads();
  const float frob2 = scal[0];
  const float trE   = scal[1];
  float wscale = 1.f;
  const float* wmLds;
  if (frob2 < 0.04f){
    // ||E||_F < 0.2: NS at T=10 is machine-converged -> wm = (I+E)^(-1/2) via series
    mm_AtB(bufE, bufE, bufA, 1.f, nullptr, 0.f);   // E^2
    mm_AtB(bufA, bufE, bufB, 1.f, nullptr, 0.f);   // E^3
    for (int idx=t; idx<4096; idx+=256){
      const int r = idx >> 6, c = idx & 63;
      bufB[idx] = ((r==c)?1.f:0.f) - 0.5f*bufE[idx] + 0.375f*bufA[idx] - 0.3125f*bufB[idx];
    }
    mm_AtB(bufA, bufA, bufE, 1.f, nullptr, 0.f);   // E^4 (barrier-safe overwrite)
    for (int idx=t; idx<4096; idx+=256)
      bufB[idx] += 0.2734375f*bufE[idx];           // 35/128
    wmLds = bufB;
  } else {
    // robust fallback: exact Newton-Schulz, 10 iterations
    const float rTr = 1.f/(trE + 64.f);
    for (int idx=t; idx<4096; idx+=256){
      const int r = idx >> 6, c = idx & 63;
      bufE[idx] = (bufE[idx] + ((r==c)?1.f:0.f))*rTr;   // Sigma_N
      bufA[idx] = (r==c)?1.f:0.f;                        // P = I
    }
    __syncthreads();
    for (int it=0; it<10; ++it){
      mm_AtB(bufA, bufE, bufB, 1.f, nullptr, 0.f);   // T1 = P@SigmaN
      mm_AtB(bufA, bufB, bufB, 1.f, nullptr, 0.f);   // T2 = P@T1
      mm_AtB(bufA, bufB, bufA, -0.5f, bufA, 1.5f);   // P = 1.5P - 0.5*P@T2
    }
    wscale = sqrtf(rTr);
    wmLds = bufA;
  }
  __syncthreads();
  for (int idx=t; idx<4096; idx+=256) WM[idx] = wmLds[idx]*wscale;
  if (t < 64){
    float d = 0.f;
    for (int j=0;j<64;++j) d += wmLds[t*64 + j]*meanv[j];
    OFS[t] = beta[t] - d*wscale;
  }
}

// ---------------- K3: apply whitening, write fp32 ----------------
__global__ __launch_bounds__(256) void k3_apply(const float* __restrict__ X,
                                                const float* __restrict__ WM,
                                                const float* __restrict__ OFS,
                                                float* __restrict__ out){
  __shared__ __align__(16) float tile[64*256];   // [c][p] natural layout
  const int t = threadIdx.x;
  const int w = __builtin_amdgcn_readfirstlane((int)(t >> 6));
  const int l = t & 63;
  const int pix = blockIdx.x*256 + 4*l;
  const int b = pix / HW;
  const int hw = pix - b*HW;
  const float* Xb = X + (size_t)b*(CH*HW) + hw;
#pragma unroll
  for (int k=0;k<16;++k){
    const int c = 4*k + w;
    const float4 v = *(const float4*)(Xb + (size_t)c*HW);
    *(float4*)&tile[c*256 + 4*l] = v;
  }
  __syncthreads();
  const int c0 = 16*w;
  float acc[16][4];
#pragma unroll
  for (int i=0;i<16;++i){ acc[i][0]=0.f; acc[i][1]=0.f; acc[i][2]=0.f; acc[i][3]=0.f; }
  for (int k=0;k<64;++k){
    const float4 xv = *(const float4*)&tile[k*256 + 4*l];
#pragma unroll
    for (int i=0;i<16;++i){
      const float wv = WM[(c0+i)*64 + k];   // wave-uniform -> s_load
      acc[i][0] += wv*xv.x; acc[i][1] += wv*xv.y;
      acc[i][2] += wv*xv.z; acc[i][3] += wv*xv.w;
    }
  }
  float* ob = out + (size_t)b*(CH*HW) + hw;
#pragma unroll
  for (int i=0;i<16;++i){
    const float o = OFS[c0+i];
    float4 pk;
    pk.x = acc[i][0]+o; pk.y = acc[i][1]+o;
    pk.z = acc[i][2]+o; pk.w = acc[i][3]+o;
    *(float4*)(ob + (size_t)(c0+i)*HW) = pk;
  }
}

extern "C" void kernel_launch(void* const* d_in, const int* in_sizes, int n_in,
                              void* d_out, int out_size, void* d_ws, size_t ws_size,
                              hipStream_t stream){
  const float* X    = (const float*)d_in[0];
  const float* beta = (const float*)d_in[1];
  float* out = (float*)d_out;
  float* ws  = (float*)d_ws;
  float* SR  = ws;            // 4160 floats (4096 raw moments + 64 channel sums)
  float* WM  = ws + 4160;     // 4096
  float* OFS = WM + 4096;     // 64
  hipMemsetAsync(SR, 0, 4160*sizeof(float), stream);
  hipLaunchKernelGGL(k1_cov,   dim3(784),  dim3(256), 0, stream, X, SR);
  hipLaunchKernelGGL(k2_wm,    dim3(1),    dim3(256), 0, stream, SR, beta, WM, OFS);
  hipLaunchKernelGGL(k3_apply, dim3(1568), dim3(256), 0, stream, X, WM, OFS, out);
}

// Round 2
// 250.482 us; speedup vs baseline: 1.0673x; 1.0405x over previous
//
#include <hip/hip_runtime.h>

#define CH 64
#define HW 3136
#define MTOT 401408   // 128*3136

typedef __attribute__((ext_vector_type(8))) short short8;   // 8 bf16 (4 VGPRs)
typedef __attribute__((ext_vector_type(4))) float f32x4;
typedef __attribute__((ext_vector_type(4))) unsigned int u32x4;

// ---------------- K1: covariance via split-bf16 MFMA ----------------
__device__ __forceinline__ void split8(const float4 a, const float4 b,
                                       short8& hi, short8& lo, float& ssum){
  const float f[8] = {a.x,a.y,a.z,a.w, b.x,b.y,b.z,b.w};
  u32x4 hp, lp;
#pragma unroll
  for (int j=0;j<4;++j){
    const unsigned int b0 = __float_as_uint(f[2*j]);
    const unsigned int b1 = __float_as_uint(f[2*j+1]);
    hp[j] = (b0 >> 16) | (b1 & 0xFFFF0000u);
    const float h0 = __uint_as_float(b0 & 0xFFFF0000u);
    const float h1 = __uint_as_float(b1 & 0xFFFF0000u);
    const unsigned int l0 = __float_as_uint(f[2*j]   - h0);
    const unsigned int l1 = __float_as_uint(f[2*j+1] - h1);
    lp[j] = (l0 >> 16) | (l1 & 0xFFFF0000u);
  }
  hi = __builtin_bit_cast(short8, hp);
  lo = __builtin_bit_cast(short8, lp);
  ssum += ((f[0]+f[1])+(f[2]+f[3])) + ((f[4]+f[5])+(f[6]+f[7]));
}

__global__ __launch_bounds__(256) void k1_cov(const float* __restrict__ X,
                                              float* __restrict__ SR){
  constexpr int RG[10] = {0,1,1,2,2,2,3,3,3,3};
  constexpr int CG[10] = {0,0,1,0,1,2,0,1,2,3};
  __shared__ float red[4096];
  __shared__ float chs[64];

  const int t   = threadIdx.x;
  const int wid = __builtin_amdgcn_readfirstlane(t >> 6);
  const int l   = t & 63;
  const int wg  = blockIdx.x * 4 + wid;          // 0..3135
  const int lrow = l & 15;
  const int lk   = (l >> 4) * 8;

  f32x4 acc[10];
#pragma unroll
  for (int bi=0; bi<10; ++bi) acc[bi] = (f32x4){0.f,0.f,0.f,0.f};
  float sums[4] = {0.f,0.f,0.f,0.f};

  for (int i=0; i<4; ++i){
    const int s = wg*4 + i;                      // 0..12543
    const int b = s / 98;
    const int p = (s - b*98) * 32;
    const float* base = X + (size_t)b*(CH*HW) + p + lrow*HW + lk;
    short8 fh[4], fl[4];
#pragma unroll
    for (int g=0; g<4; ++g){
      const float* pg = base + (size_t)g*16*HW;
      const float4 v0 = *(const float4*)pg;
      const float4 v1 = *(const float4*)(pg + 4);
      split8(v0, v1, fh[g], fl[g], sums[g]);
    }
#pragma unroll
    for (int bi=0; bi<10; ++bi){
      acc[bi] = __builtin_amdgcn_mfma_f32_16x16x32_bf16(fh[RG[bi]], fh[CG[bi]], acc[bi], 0,0,0);
      acc[bi] = __builtin_amdgcn_mfma_f32_16x16x32_bf16(fh[RG[bi]], fl[CG[bi]], acc[bi], 0,0,0);
      acc[bi] = __builtin_amdgcn_mfma_f32_16x16x32_bf16(fl[RG[bi]], fh[CG[bi]], acc[bi], 0,0,0);
    }
  }

#pragma unroll
  for (int g=0; g<4; ++g){
    sums[g] += __shfl_xor(sums[g], 16);
    sums[g] += __shfl_xor(sums[g], 32);
  }

  for (int w=0; w<4; ++w){
    if (wid == w){
#pragma unroll
      for (int bi=0; bi<10; ++bi){
        const int row0 = RG[bi]*16 + 4*(l>>4);
        const int col  = CG[bi]*16 + (l&15);
#pragma unroll
        for (int r=0; r<4; ++r){
          float* d = &red[(row0+r)*64 + col];
          if (w==0) *d = acc[bi][r]; else *d += acc[bi][r];
        }
      }
      if (l < 16){
#pragma unroll
        for (int g=0; g<4; ++g){
          if (w==0) chs[g*16+l] = sums[g]; else chs[g*16+l] += sums[g];
        }
      }
    }
    __syncthreads();
  }

#pragma unroll
  for (int bi=0; bi<10; ++bi){
    const int r = RG[bi]*16 + (t>>4);
    const int c = CG[bi]*16 + (t&15);
    unsafeAtomicAdd(&SR[r*64+c], red[r*64+c]);
  }
  if (t < 64) unsafeAtomicAdd(&SR[4096+t], chs[t]);
}

// ---------------- K2: whitening matrix ----------------
__device__ __forceinline__ void mm_AtB(const float* a, const float* b, float* out,
                                       float alpha, const float* aff, float beta_){
  const int t = threadIdx.x;
  const int c2 = 2*(t & 31);
  const int r0 = 8*(t >> 5);
  float acc[8][2];
#pragma unroll
  for (int i=0;i<8;++i){ acc[i][0]=0.f; acc[i][1]=0.f; }
  for (int k=0;k<64;++k){
    const float2 bv = *(const float2*)&b[k*64 + c2];
    const float4 a0 = *(const float4*)&a[k*64 + r0];
    const float4 a1 = *(const float4*)&a[k*64 + r0 + 4];
    const float av[8] = {a0.x,a0.y,a0.z,a0.w, a1.x,a1.y,a1.z,a1.w};
#pragma unroll
    for (int i=0;i<8;++i){ acc[i][0] += av[i]*bv.x; acc[i][1] += av[i]*bv.y; }
  }
  float res[8][2];
#pragma unroll
  for (int i=0;i<8;++i){
    float f0 = alpha*acc[i][0], f1 = alpha*acc[i][1];
    if (aff){ f0 += beta_*aff[(r0+i)*64 + c2]; f1 += beta_*aff[(r0+i)*64 + c2 + 1]; }
    res[i][0]=f0; res[i][1]=f1;
  }
  __syncthreads();
#pragma unroll
  for (int i=0;i<8;++i){
    float2 o2; o2.x = res[i][0]; o2.y = res[i][1];
    *(float2*)&out[(r0+i)*64 + c2] = o2;
  }
  __syncthreads();
}

__global__ __launch_bounds__(256) void k2_wm(const float* __restrict__ SR,
                                             const float* __restrict__ beta,
                                             float* __restrict__ WMT,
                                             float* __restrict__ OFS){
  __shared__ __align__(16) float bufE[4096];
  __shared__ __align__(16) float bufA[4096];
  __shared__ __align__(16) float bufB[4096];
  __shared__ float meanv[64];
  __shared__ float scal[2];
  const int t = threadIdx.x;
  const float inv_m = 1.f/(float)MTOT;
  if (t < 64) meanv[t] = SR[4096 + t]*inv_m;
  __syncthreads();
  // SR holds only the lower-triangle 16x16 blocks: symmetrize on load.
  for (int idx=t; idx<4096; idx+=256){
    const int r = idx >> 6, c = idx & 63;
    const int src = ((r >> 4) >= (c >> 4)) ? idx : (c*64 + r);
    const float cov = SR[src]*inv_m - meanv[r]*meanv[c];
    bufE[idx] = (r==c) ? (cov + 1e-5f - 1.f) : 0.9f*cov;
  }
  __syncthreads();
  float n2 = 0.f, tr = 0.f;
  for (int idx=t; idx<4096; idx+=256){
    const float e = bufE[idx];
    n2 += e*e;
    if ((idx >> 6) == (idx & 63)) tr += e;
  }
  bufA[t] = n2; bufB[t] = tr;
  __syncthreads();
  if (t < 64){
    bufA[t] = bufA[t]+bufA[t+64]+bufA[t+128]+bufA[t+192];
    bufB[t] = bufB[t]+bufB[t+64]+bufB[t+128]+bufB[t+192];
  }
  __syncthreads();
  if (t == 0){
    float s1=0.f, s2=0.f;
    for (int i=0;i<64;++i){ s1 += bufA[i]; s2 += bufB[i]; }
    scal[0] = s1; scal[1] = s2;
  }
  __syncthreads();
  const float frob2 = scal[0];
  const float trE   = scal[1];
  float wscale = 1.f;
  const float* wmLds;
  if (frob2 < 0.04f){
    // ||E||_F < 0.2: wm = (I+E)^(-1/2) via 4th-order series (== NS@T=10 limit)
    mm_AtB(bufE, bufE, bufA, 1.f, nullptr, 0.f);   // E^2
    mm_AtB(bufA, bufE, bufB, 1.f, nullptr, 0.f);   // E^3
    for (int idx=t; idx<4096; idx+=256){
      const int r = idx >> 6, c = idx & 63;
      bufB[idx] = ((r==c)?1.f:0.f) - 0.5f*bufE[idx] + 0.375f*bufA[idx] - 0.3125f*bufB[idx];
    }
    mm_AtB(bufA, bufA, bufE, 1.f, nullptr, 0.f);   // E^4 (barrier-safe overwrite)
    for (int idx=t; idx<4096; idx+=256)
      bufB[idx] += 0.2734375f*bufE[idx];           // 35/128
    wmLds = bufB;
  } else {
    // robust fallback: exact Newton-Schulz, 10 iterations
    const float rTr = 1.f/(trE + 64.f);
    for (int idx=t; idx<4096; idx+=256){
      const int r = idx >> 6, c = idx & 63;
      bufE[idx] = (bufE[idx] + ((r==c)?1.f:0.f))*rTr;   // Sigma_N
      bufA[idx] = (r==c)?1.f:0.f;                        // P = I
    }
    __syncthreads();
    for (int it=0; it<10; ++it){
      mm_AtB(bufA, bufE, bufB, 1.f, nullptr, 0.f);
      mm_AtB(bufA, bufB, bufB, 1.f, nullptr, 0.f);
      mm_AtB(bufA, bufB, bufA, -0.5f, bufA, 1.5f);
    }
    wscale = sqrtf(rTr);
    wmLds = bufA;
  }
  __syncthreads();
  // WMT[k][c] = wm[c][k]*wscale  (transposed so k3 reads 16 contiguous floats per k)
  for (int idx=t; idx<4096; idx+=256)
    WMT[(idx & 63)*64 + (idx >> 6)] = wmLds[idx]*wscale;
  if (t < 64){
    float d = 0.f;
    for (int j=0;j<64;++j) d += wmLds[t*64 + j]*meanv[j];
    OFS[t] = beta[t] - d*wscale;
  }
}

// ---------------- K3: apply whitening ----------------
// 128-px tile (32KB LDS -> 4 blocks/CU), global_load_lds staging (no VGPR
// round-trip), WMT gives contiguous per-k scalar loads (s_load_dwordx4 merge).
#define PXT 128
__global__ __launch_bounds__(256, 4) void k3_apply(const float* __restrict__ X,
                                                   const float* __restrict__ WMT,
                                                   const float* __restrict__ OFS,
                                                   float* __restrict__ out){
  __shared__ __align__(16) float tile[64*PXT];   // [c][128px] = 32KB
  const int t = threadIdx.x;
  const int w = __builtin_amdgcn_readfirstlane((int)(t >> 6));
  const int l = t & 63;
  const int pxbase = blockIdx.x * PXT;

  // ---- stage: 8 x global_load_lds per wave, 2 rows (2x512B = 1KB) per instr ----
  {
    const int half = l >> 5;                 // 0/1: second row of the pair
    const int P    = pxbase + 4*(l & 31);    // this lane's global pixel
    const int b    = P / HW;
    const int hw   = P - b*HW;
    const float* src0 = X + (size_t)b*(CH*HW) + hw;
#pragma unroll
    for (int j=0;j<8;++j){
      const int cr = 16*w + 2*j;             // row pair base (wave-uniform)
      __builtin_amdgcn_global_load_lds(
        (const __attribute__((address_space(1))) unsigned int*)(src0 + (size_t)(cr + half)*HW),
        (__attribute__((address_space(3))) unsigned int*)&tile[cr*PXT],
        16, 0, 0);
    }
  }
  asm volatile("s_waitcnt vmcnt(0)" ::: "memory");
  __syncthreads();

  // ---- compute: each wave does 16 channels x 2 px per lane ----
  const int c0 = 16*w;
  float acc[16][2];
#pragma unroll
  for (int i=0;i<16;++i){ acc[i][0]=0.f; acc[i][1]=0.f; }
  for (int k=0;k<64;++k){
    const float2 xv = *(const float2*)&tile[k*PXT + 2*l];
    const float* wr = &WMT[k*64 + c0];       // 16 contiguous, wave-uniform
#pragma unroll
    for (int i=0;i<16;++i){
      acc[i][0] += wr[i]*xv.x;
      acc[i][1] += wr[i]*xv.y;
    }
  }

  // ---- write ----
  const int P2  = pxbase + 2*l;
  const int b2  = P2 / HW;
  const int hw2 = P2 - b2*HW;
  float* ob = out + (size_t)b2*(CH*HW) + hw2;
#pragma unroll
  for (int i=0;i<16;++i){
    const float o = OFS[c0+i];
    float2 pk; pk.x = acc[i][0]+o; pk.y = acc[i][1]+o;
    *(float2*)(ob + (size_t)(c0+i)*HW) = pk;
  }
}

extern "C" void kernel_launch(void* const* d_in, const int* in_sizes, int n_in,
                              void* d_out, int out_size, void* d_ws, size_t ws_size,
                              hipStream_t stream){
  const float* X    = (const float*)d_in[0];
  const float* beta = (const float*)d_in[1];
  float* out = (float*)d_out;
  float* ws  = (float*)d_ws;
  float* SR  = ws;            // 4160 floats (4096 raw moments + 64 channel sums)
  float* WMT = ws + 4160;     // 4096 (transposed, pre-scaled whitening matrix)
  float* OFS = WMT + 4096;    // 64
  hipMemsetAsync(SR, 0, 4160*sizeof(float), stream);
  hipLaunchKernelGGL(k1_cov,   dim3(784),  dim3(256), 0, stream, X, SR);
  hipLaunchKernelGGL(k2_wm,    dim3(1),    dim3(256), 0, stream, SR, beta, WMT, OFS);
  hipLaunchKernelGGL(k3_apply, dim3(3136), dim3(256), 0, stream, X, WMT, OFS, out);
}